// Round 6
// baseline (272.363 us; speedup 1.0000x reference)
//
#include <hip/hip_runtime.h>

// VanillaRNN: B=4096, T=1024, I=3, H=32, O=2
// out[b,t,j] = h_t[j];  h_t = tanh(x_t @ W_ih^T + b_ih + b_hh + h_{t-1} @ W_hh^T)
// h_n[b,o] = h_T @ W_fc^T + b_fc
//
// R5: R4b layout (16 lanes/batch, lane owns j=2p,2p+1; register-only exchange
// via independent dpp row_ror:m), with stall fixes:
//  - regular cached stores (nontemporal bypassed L2 -> ~900cyc HBM ack on the
//    in-order vmcnt queue; cached acks at L2 ~200cyc, write-back off-path)
//  - DEPTH 8 (x-load wait once per 8 steps, 2x prefetch distance)
//  - 4 independent 8-deep acc chains (dep-latency bubbles fillable by 1 wave)

typedef float f2 __attribute__((ext_vector_type(2)));

#define RNN_B 4096
#define RNN_T 1024
#define RNN_H 32
#define GROUPS 16             // batches per block (16-lane groups)
#define BLOCK 256
#define DEPTH 8               // T-unroll / x prefetch distance

#define SCALE 2.8853900817779268f   // 2*log2(e)

template <int M>
__device__ __forceinline__ f2 rotm(f2 v) {
    // DPP row_ror:M — lane i reads lane (i-M)&15 within its 16-lane row
    f2 r;
    r.x = __int_as_float(__builtin_amdgcn_mov_dpp(__float_as_int(v.x), 0x120 | M, 0xf, 0xf, true));
    r.y = __int_as_float(__builtin_amdgcn_mov_dpp(__float_as_int(v.y), 0x120 | M, 0xf, 0xf, true));
    return r;
}

__global__ __launch_bounds__(BLOCK) void vanilla_rnn_kernel(
    const float* __restrict__ x,     // [B,T,3]
    const float* __restrict__ W_ih,  // [32,3]
    const float* __restrict__ b_ih,  // [32]
    const float* __restrict__ W_hh,  // [32,32]
    const float* __restrict__ b_hh,  // [32]
    const float* __restrict__ W_fc,  // [2,32]
    const float* __restrict__ b_fc,  // [2]
    float* __restrict__ out,         // [B,T,32]
    float* __restrict__ hn_out)      // [B,2]
{
    const int tid = threadIdx.x;
    const int g   = tid >> 4;        // batch group within block
    const int p   = tid & 15;        // pair position within 16-lane row
    const int b   = blockIdx.x * GROUPS + g;
    const int j0  = 2 * p;
    const int j1  = 2 * p + 1;

    __shared__ float hs[GROUPS][32]; // epilogue only

    // W_hh rows j0,j1 in rotation order (pair q=(p-m)&15), pre-scaled.
    f2 Wa[16], Wb[16];
#pragma unroll
    for (int m = 0; m < 16; ++m) {
        const int q = (p - m) & 15;
        Wa[m].x = W_hh[j0 * 32 + 2 * q]     * SCALE;
        Wa[m].y = W_hh[j0 * 32 + 2 * q + 1] * SCALE;
        Wb[m].x = W_hh[j1 * 32 + 2 * q]     * SCALE;
        Wb[m].y = W_hh[j1 * 32 + 2 * q + 1] * SCALE;
    }

    // x-projection constants for both owned outputs (.x -> j0, .y -> j1)
    f2 wi0, wi1, wi2, bs;
    wi0.x = W_ih[j0 * 3 + 0] * SCALE;  wi0.y = W_ih[j1 * 3 + 0] * SCALE;
    wi1.x = W_ih[j0 * 3 + 1] * SCALE;  wi1.y = W_ih[j1 * 3 + 1] * SCALE;
    wi2.x = W_ih[j0 * 3 + 2] * SCALE;  wi2.y = W_ih[j1 * 3 + 2] * SCALE;
    bs.x  = (b_ih[j0] + b_hh[j0]) * SCALE;
    bs.y  = (b_ih[j1] + b_hh[j1]) * SCALE;

    const float* xb = x + (size_t)b * RNN_T * 3;
    float*       ob = out + (size_t)b * RNN_T * RNN_H;

    float xs[DEPTH][3];
#pragma unroll
    for (int d = 0; d < DEPTH; ++d)
#pragma unroll
        for (int c = 0; c < 3; ++c) xs[d][c] = xb[d * 3 + c];

    float hj0 = 0.0f, hj1 = 0.0f;

    for (int tb = 0; tb < RNN_T; tb += DEPTH) {
        const int tnb = (tb + DEPTH < RNN_T) ? (tb + DEPTH) : tb;
        float nxs[DEPTH][3];
#pragma unroll
        for (int d = 0; d < DEPTH; ++d)
#pragma unroll
            for (int c = 0; c < 3; ++c) nxs[d][c] = xb[(tnb + d) * 3 + c];

        // pre-scaled x-projection for this block (h-independent)
        f2 xp[DEPTH];
#pragma unroll
        for (int d = 0; d < DEPTH; ++d) {
            f2 v = bs;
            v = __builtin_elementwise_fma(wi0, (f2){xs[d][0], xs[d][0]}, v);
            v = __builtin_elementwise_fma(wi1, (f2){xs[d][1], xs[d][1]}, v);
            v = __builtin_elementwise_fma(wi2, (f2){xs[d][2], xs[d][2]}, v);
            xp[d] = v;
        }

#pragma unroll
        for (int d = 0; d < DEPTH; ++d) {
            f2 hp; hp.x = hj0; hp.y = hj1;

            // 4 independent 8-deep chains: aA0/aA1 (output j0), aB0/aB1 (j1)
            f2 aA0, aA1, aB0, aB1;
            aA0.x = xp[d].x; aA0.y = 0.0f;
            aA1.x = 0.0f;    aA1.y = 0.0f;
            aB0.x = xp[d].y; aB0.y = 0.0f;
            aB1.x = 0.0f;    aB1.y = 0.0f;

            aA0 = __builtin_elementwise_fma(hp, Wa[0], aA0);
            aB0 = __builtin_elementwise_fma(hp, Wb[0], aB0);
#define ROT_STEP(M, AA, BB)                                        \
            {                                                      \
                const f2 r = rotm<M>(hp);                          \
                AA = __builtin_elementwise_fma(r, Wa[M], AA);      \
                BB = __builtin_elementwise_fma(r, Wb[M], BB);      \
            }
            ROT_STEP(1,  aA1, aB1)  ROT_STEP(2,  aA0, aB0)
            ROT_STEP(3,  aA1, aB1)  ROT_STEP(4,  aA0, aB0)
            ROT_STEP(5,  aA1, aB1)  ROT_STEP(6,  aA0, aB0)
            ROT_STEP(7,  aA1, aB1)  ROT_STEP(8,  aA0, aB0)
            ROT_STEP(9,  aA1, aB1)  ROT_STEP(10, aA0, aB0)
            ROT_STEP(11, aA1, aB1)  ROT_STEP(12, aA0, aB0)
            ROT_STEP(13, aA1, aB1)  ROT_STEP(14, aA0, aB0)
            ROT_STEP(15, aA1, aB1)
#undef ROT_STEP

            const f2 sa = aA0 + aA1;
            const f2 sb = aB0 + aB1;
            const float ya = sa.x + sa.y;   // = 2*log2e * (pre-tanh)
            const float yb = sb.x + sb.y;

            // tanh(z) = 1 - 2/(exp2(2*log2e*z)+1); inf-safe
            const float ea = exp2f(ya);
            const float eb = exp2f(yb);
            const float tha = fmaf(-2.0f, __builtin_amdgcn_rcpf(ea + 1.0f), 1.0f);
            const float thb = fmaf(-2.0f, __builtin_amdgcn_rcpf(eb + 1.0f), 1.0f);

            f2 st; st.x = tha; st.y = thb;
            *(reinterpret_cast<f2*>(ob + (size_t)(tb + d) * RNN_H) + p) = st;

            hj0 = tha; hj1 = thb;
        }

#pragma unroll
        for (int d = 0; d < DEPTH; ++d)
#pragma unroll
            for (int c = 0; c < 3; ++c) xs[d][c] = nxs[d][c];
    }

    // h_n = h_T @ W_fc^T + b_fc  (16-lane group is wave-internal, no barrier)
    hs[g][j0] = hj0;
    hs[g][j1] = hj1;
    if (p < 2) {
        float acc = b_fc[p];
#pragma unroll
        for (int k = 0; k < 32; ++k) acc = fmaf(W_fc[p * 32 + k], hs[g][k], acc);
        hn_out[(size_t)b * 2 + p] = acc;
    }
}

extern "C" void kernel_launch(void* const* d_in, const int* in_sizes, int n_in,
                              void* d_out, int out_size, void* d_ws, size_t ws_size,
                              hipStream_t stream) {
    const float* x    = (const float*)d_in[0];
    const float* W_ih = (const float*)d_in[1];
    const float* b_ih = (const float*)d_in[2];
    const float* W_hh = (const float*)d_in[3];
    const float* b_hh = (const float*)d_in[4];
    const float* W_fc = (const float*)d_in[5];
    const float* b_fc = (const float*)d_in[6];

    float* out    = (float*)d_out;                                   // [B,T,H]
    float* hn_out = out + (size_t)RNN_B * RNN_T * RNN_H;             // [B,2]

    const int grid = RNN_B / GROUPS;  // 256 blocks
    vanilla_rnn_kernel<<<grid, BLOCK, 0, stream>>>(
        x, W_ih, b_ih, W_hh, b_hh, W_fc, b_fc, out, hn_out);
}